// Round 2
// baseline (983.150 us; speedup 1.0000x reference)
//
#include <hip/hip_runtime.h>
#include <cstdint>
#include <cstddef>

typedef unsigned short u16;
typedef __attribute__((ext_vector_type(8))) __bf16 bf16x8;
typedef __attribute__((ext_vector_type(4))) float f32x4;

#define S_LEN   2048
#define H_DIM   4096
#define NH_N    32
#define HD_N    128
#define QKV_LD  12288   // 3*H

// round-to-nearest-even fp32 -> bf16 (bit pattern)
__device__ __forceinline__ u16 f2b(float f) {
  union { float f; unsigned u; } v; v.f = f;
  unsigned r = v.u + 0x7fffu + ((v.u >> 16) & 1u);
  return (u16)(r >> 16);
}

// async global->LDS, 16B per lane; LDS dest = wave-uniform base + lane*16
__device__ __forceinline__ void gl2lds16(const void* g, void* l) {
  __builtin_amdgcn_global_load_lds((__attribute__((address_space(1))) void*)g,
                                   (__attribute__((address_space(3))) void*)l,
                                   16, 0, 0);
}

// ---------------------------------------------------------------- fp32->bf16
__global__ __launch_bounds__(256) void cvt_kernel(const float* __restrict__ src,
                                                  u16* __restrict__ dst, int n8) {
  int i = blockIdx.x * 256 + threadIdx.x;
  if (i >= n8) return;
  const float4* s4 = (const float4*)src;
  float4 a = s4[i * 2], b = s4[i * 2 + 1];
  union { u16 o[8]; uint4 v; } u;
  u.o[0] = f2b(a.x); u.o[1] = f2b(a.y); u.o[2] = f2b(a.z); u.o[3] = f2b(a.w);
  u.o[4] = f2b(b.x); u.o[5] = f2b(b.y); u.o[6] = f2b(b.z); u.o[7] = f2b(b.w);
  ((uint4*)dst)[i] = u.v;
}

// ------------------------------------------------------------------- GEMM
// C = A(MxK,bf16) * B(NxK,bf16)^T + bias ;  OUTF32: +residual -> f32 out
template <int OUTF32>
__global__ __launch_bounds__(256, 2)
void gemm_kernel(const u16* __restrict__ A, const u16* __restrict__ B,
                 const float* __restrict__ bias, const float* __restrict__ resid,
                 u16* __restrict__ outB, float* __restrict__ outF,
                 int M, int N, int K) {
  __shared__ __align__(16) u16 As[128 * 64];
  __shared__ __align__(16) u16 Bs[128 * 64];
  const int tid  = threadIdx.x;
  const int lane = tid & 63;
  const int wave = tid >> 6;
  const int l15  = lane & 15;
  const int quad = lane >> 4;
  const int m0 = blockIdx.y * 128;
  const int n0 = blockIdx.x * 128;
  const int wm = (wave & 1) * 64;
  const int wn = (wave >> 1) * 64;

  f32x4 acc[4][4] = {};

  int sRow[4], sCol[4];
#pragma unroll
  for (int it = 0; it < 4; ++it) {
    int slot = wave * 256 + it * 64 + lane;
    int row  = slot >> 3;
    int kc   = (slot & 7) ^ (row & 7);
    sRow[it] = row;
    sCol[it] = kc * 8;
  }
  const u16* Ag = A + (size_t)m0 * K;
  const u16* Bg = B + (size_t)n0 * K;

  for (int kb = 0; kb < K; kb += 64) {
#pragma unroll
    for (int it = 0; it < 4; ++it) {
      int base = (wave * 256 + it * 64) * 8;
      gl2lds16(Ag + (size_t)sRow[it] * K + kb + sCol[it], &As[base]);
      gl2lds16(Bg + (size_t)sRow[it] * K + kb + sCol[it], &Bs[base]);
    }
    __syncthreads();
#pragma unroll
    for (int s = 0; s < 2; ++s) {
      const int kc = s * 4 + quad;
      bf16x8 af[4], bfr[4];
#pragma unroll
      for (int i = 0; i < 4; ++i) {
        int ra = wm + i * 16 + l15;
        af[i]  = *(const bf16x8*)&As[(ra * 8 + (kc ^ (ra & 7))) * 8];
        int rb = wn + i * 16 + l15;
        bfr[i] = *(const bf16x8*)&Bs[(rb * 8 + (kc ^ (rb & 7))) * 8];
      }
#pragma unroll
      for (int i = 0; i < 4; ++i)
#pragma unroll
        for (int j = 0; j < 4; ++j)
          acc[i][j] = __builtin_amdgcn_mfma_f32_16x16x32_bf16(af[i], bfr[j], acc[i][j], 0, 0, 0);
    }
    __syncthreads();
  }

  float bcol[4];
#pragma unroll
  for (int j = 0; j < 4; ++j) bcol[j] = bias[n0 + wn + j * 16 + l15];
#pragma unroll
  for (int i = 0; i < 4; ++i) {
    int rowb = m0 + wm + i * 16 + quad * 4;
#pragma unroll
    for (int r = 0; r < 4; ++r) {
      size_t rowoff = (size_t)(rowb + r) * N;
#pragma unroll
      for (int j = 0; j < 4; ++j) {
        int col = n0 + wn + j * 16 + l15;
        float v = acc[i][j][r] + bcol[j];
        if (OUTF32) outF[rowoff + col] = v + resid[rowoff + col];
        else        outB[rowoff + col] = f2b(v);
      }
    }
  }
}

// ------------------------------------------------------------- attention
// Block b handles q-tiles {b, 31-b} (uniform 33 compute-units/block).
// Double-buffered K/V staging, one barrier per k-tile; staging overlaps
// compute. kf/vf LDS reads shared between the two q-groups.
__global__ __launch_bounds__(256, 2)
void attn_kernel(const u16* __restrict__ QKV, const float* __restrict__ alibi,
                 u16* __restrict__ CTX) {
  __shared__ __align__(16) u16 Ks[2][64 * 128];   // swizzled [key][hd]
  __shared__ __align__(16) u16 Vt[2][128 * 64];   // swizzled [hd][key]
  __shared__ __align__(16) u16 Ps[8192];          // per-wave x 2 groups [q][key]
  const int tid  = threadIdx.x;
  const int lane = tid & 63;
  const int wave = tid >> 6;
  const int l15  = lane & 15;
  const int quad = lane >> 4;
  const int bq   = blockIdx.x;          // 0..15
  const int head = blockIdx.y;
  const int gq0  = bq;                  // first q-tile (limit kt<=gq0)
  const int gq1  = 31 - bq;             // second q-tile (always active)
  const int nk   = 32 - bq;             // iterations kt=0..31-bq
  const int qcol = head * 384;
  const int kcol = qcol + 128;
  const int vcol = qcol + 256;
  const float c1 = 0.08838834764831845f * 1.4426950408889634f;  // invsqrt(128)*log2e
  const float slope2 = alibi[head * S_LEN + 1] * 1.4426950408889634f;

  // V staging assignment: thread covers 4 consecutive keys x 8 hd
  const int keybase = (tid & 15) * 4;
  const int hd0     = (tid >> 4) * 8;

  auto stage_k = [&](int kt, int bb) {
#pragma unroll
    for (int it = 0; it < 4; ++it) {
      int slot = wave * 256 + it * 64 + lane;
      int row  = slot >> 4;
      int hdc  = (slot & 15) ^ (row & 15);
      gl2lds16(QKV + (size_t)(kt * 64 + row) * QKV_LD + kcol + hdc * 8,
               &Ks[bb][(wave * 256 + it * 64) * 8]);
    }
  };
  auto load_v = [&](int kt, uint4* vr) {
    const u16* vp = QKV + (size_t)(kt * 64 + keybase) * QKV_LD + vcol + hd0;
#pragma unroll
    for (int j = 0; j < 4; ++j) vr[j] = *(const uint4*)(vp + (size_t)j * QKV_LD);
  };
  auto write_v = [&](int bb, const uint4* vr) {
    const u16* e0 = (const u16*)&vr[0];
    const u16* e1 = (const u16*)&vr[1];
    const u16* e2 = (const u16*)&vr[2];
    const u16* e3 = (const u16*)&vr[3];
#pragma unroll
    for (int u = 0; u < 8; ++u) {
      int hd = hd0 + u;     // hd&7 == u
      uint2 w;
      w.x = (unsigned)e0[u] | ((unsigned)e1[u] << 16);
      w.y = (unsigned)e2[u] | ((unsigned)e3[u] << 16);
      *(uint2*)&Vt[bb][hd * 64 + ((keybase >> 3) ^ u) * 8 + (keybase & 7)] = w;
    }
  };

  // Q fragments for both groups stay in registers
  bf16x8 qf[2][4];
#pragma unroll
  for (int g = 0; g < 2; ++g) {
    const int gqt = (g == 0) ? gq0 : gq1;
    const u16* qp = QKV + (size_t)(gqt * 64 + wave * 16 + l15) * QKV_LD + qcol;
#pragma unroll
    for (int s = 0; s < 4; ++s) qf[g][s] = *(const bf16x8*)(qp + s * 32 + quad * 8);
  }

  float m_i[2][4], l_i[2][4];
#pragma unroll
  for (int g = 0; g < 2; ++g)
#pragma unroll
    for (int r = 0; r < 4; ++r) { m_i[g][r] = -3.0e38f; l_i[g][r] = 0.0f; }
  f32x4 acc[2][8] = {};

  // prologue: stage tile 0 into buffer 0
  {
    stage_k(0, 0);
    uint4 vr[4];
    load_v(0, vr);
    write_v(0, vr);
    __syncthreads();
  }

  for (int kt = 0; kt < nk; ++kt) {
    const int cur = kt & 1;
    const int nxt = cur ^ 1;
    const bool more = (kt + 1 < nk);
    uint4 vr[4];
    if (more) { stage_k(kt + 1, nxt); load_v(kt + 1, vr); }

    const int k0 = kt * 64;
    const u16* Ksc = Ks[cur];
    const u16* Vtc = Vt[cur];
    const bool a0 = (kt <= gq0);

    // Q*K^T for both groups, kf shared
    f32x4 sc[2][4] = {};
#pragma unroll
    for (int s = 0; s < 4; ++s) {
      const int kc = s * 4 + quad;
      bf16x8 kf[4];
#pragma unroll
      for (int j = 0; j < 4; ++j) {
        int row = j * 16 + l15;
        kf[j] = *(const bf16x8*)&Ksc[(row * 16 + (kc ^ (row & 15))) * 8];
      }
#pragma unroll
      for (int j = 0; j < 4; ++j) {
        sc[1][j] = __builtin_amdgcn_mfma_f32_16x16x32_bf16(qf[1][s], kf[j], sc[1][j], 0, 0, 0);
        if (a0)
          sc[0][j] = __builtin_amdgcn_mfma_f32_16x16x32_bf16(qf[0][s], kf[j], sc[0][j], 0, 0, 0);
      }
    }

    // online softmax per group
#pragma unroll
    for (int g = 0; g < 2; ++g) {
      if (g == 0 && !a0) continue;
      const int gqt  = (g == 0) ? gq0 : gq1;
      const bool diag = (kt == gqt);
      const int qbase = gqt * 64 + wave * 16 + quad * 4;
      float mt[4] = { -3.0e38f, -3.0e38f, -3.0e38f, -3.0e38f };
#pragma unroll
      for (int j = 0; j < 4; ++j) {
        int key  = k0 + j * 16 + l15;
        float al = slope2 * (float)key;
#pragma unroll
        for (int r = 0; r < 4; ++r) {
          float x = sc[g][j][r] * c1 + al;
          if (diag && key > qbase + r) x = -3.0e38f;
          sc[g][j][r] = x;
          mt[r] = fmaxf(mt[r], x);
        }
      }
#pragma unroll
      for (int r = 0; r < 4; ++r) {
        float v = mt[r];
        v = fmaxf(v, __shfl_xor(v, 1));
        v = fmaxf(v, __shfl_xor(v, 2));
        v = fmaxf(v, __shfl_xor(v, 4));
        v = fmaxf(v, __shfl_xor(v, 8));
        mt[r] = fmaxf(m_i[g][r], v);
      }
      float psum[4];
#pragma unroll
      for (int r = 0; r < 4; ++r) {
        float alpha = exp2f(m_i[g][r] - mt[r]);
        m_i[g][r] = mt[r];
        l_i[g][r] *= alpha;
        psum[r] = 0.0f;
#pragma unroll
        for (int t = 0; t < 8; ++t) acc[g][t][r] *= alpha;
      }
#pragma unroll
      for (int j = 0; j < 4; ++j) {
        int col = j * 16 + l15;
        int kc2 = col >> 3;
#pragma unroll
        for (int r = 0; r < 4; ++r) {
          float p = exp2f(sc[g][j][r] - m_i[g][r]);
          psum[r] += p;
          int qrow = quad * 4 + r;
          Ps[wave * 2048 + g * 1024 + (qrow * 8 + (kc2 ^ (qrow & 7))) * 8 + (col & 7)] = f2b(p);
        }
      }
#pragma unroll
      for (int r = 0; r < 4; ++r) {
        float v = psum[r];
        v += __shfl_xor(v, 1);
        v += __shfl_xor(v, 2);
        v += __shfl_xor(v, 4);
        v += __shfl_xor(v, 8);
        l_i[g][r] += v;
      }
    }

    // P*V for both groups, vf shared (same-wave LDS write->read, no barrier)
#pragma unroll
    for (int s = 0; s < 2; ++s) {
      const int kc = s * 4 + quad;
      bf16x8 pf1 = *(const bf16x8*)&Ps[wave * 2048 + 1024 + (l15 * 8 + (kc ^ (l15 & 7))) * 8];
      bf16x8 pf0 = pf1;
      if (a0) pf0 = *(const bf16x8*)&Ps[wave * 2048 + (l15 * 8 + (kc ^ (l15 & 7))) * 8];
#pragma unroll
      for (int t = 0; t < 8; ++t) {
        int row = t * 16 + l15;
        bf16x8 vf = *(const bf16x8*)&Vtc[(row * 8 + (kc ^ (row & 7))) * 8];
        acc[1][t] = __builtin_amdgcn_mfma_f32_16x16x32_bf16(pf1, vf, acc[1][t], 0, 0, 0);
        if (a0)
          acc[0][t] = __builtin_amdgcn_mfma_f32_16x16x32_bf16(pf0, vf, acc[0][t], 0, 0, 0);
      }
    }

    if (more) write_v(nxt, vr);
    __syncthreads();
  }

  // normalize and write context (bf16) in [s][n*128+d] layout for GEMM2
#pragma unroll
  for (int g = 0; g < 2; ++g) {
    const int gqt = (g == 0) ? gq0 : gq1;
#pragma unroll
    for (int r = 0; r < 4; ++r) {
      float inv = 1.0f / l_i[g][r];
      size_t rowoff = (size_t)(gqt * 64 + wave * 16 + quad * 4 + r) * H_DIM;
#pragma unroll
      for (int t = 0; t < 8; ++t)
        CTX[rowoff + head * HD_N + t * 16 + l15] = f2b(acc[g][t][r] * inv);
    }
  }
}

// ---------------------------------------------------------------- launcher
extern "C" void kernel_launch(void* const* d_in, const int* in_sizes, int n_in,
                              void* d_out, int out_size, void* d_ws, size_t ws_size,
                              hipStream_t stream) {
  const float* hidden   = (const float*)d_in[0];
  const float* residual = (const float*)d_in[1];
  const float* alibi    = (const float*)d_in[2];
  // d_in[3] attention_mask: known causal, unused
  const float* qkv_w    = (const float*)d_in[4];
  const float* qkv_b    = (const float*)d_in[5];
  const float* dense_w  = (const float*)d_in[6];
  const float* dense_b  = (const float*)d_in[7];
  float* out = (float*)d_out;

  // workspace layout (bf16): X | Wqkv | Wdense | QKV | CTX
  u16* Xb  = (u16*)d_ws;
  u16* Wq  = Xb + (size_t)S_LEN * H_DIM;
  u16* Wd  = Wq + (size_t)3 * H_DIM * H_DIM;
  u16* QKV = Wd + (size_t)H_DIM * H_DIM;
  u16* CTX = QKV + (size_t)S_LEN * 3 * H_DIM;

  {
    int n8 = S_LEN * H_DIM / 8;
    cvt_kernel<<<dim3((n8 + 255) / 256), 256, 0, stream>>>(hidden, Xb, n8);
  }
  {
    int n8 = 3 * H_DIM * H_DIM / 8;
    cvt_kernel<<<dim3((n8 + 255) / 256), 256, 0, stream>>>(qkv_w, Wq, n8);
  }
  {
    int n8 = H_DIM * H_DIM / 8;
    cvt_kernel<<<dim3((n8 + 255) / 256), 256, 0, stream>>>(dense_w, Wd, n8);
  }

  // QKV = X * Wqkv^T + b  -> bf16
  gemm_kernel<0><<<dim3(3 * H_DIM / 128, S_LEN / 128), 256, 0, stream>>>(
      Xb, Wq, qkv_b, nullptr, QKV, nullptr, S_LEN, 3 * H_DIM, H_DIM);

  // flash attention -> CTX bf16
  attn_kernel<<<dim3(16, NH_N), 256, 0, stream>>>(QKV, alibi, CTX);

  // out = CTX * Wd^T + b + residual  -> f32
  gemm_kernel<1><<<dim3(H_DIM / 128, S_LEN / 128), 256, 0, stream>>>(
      CTX, Wd, dense_b, residual, nullptr, out, S_LEN, H_DIM, H_DIM);
}

// Round 3
// 870.923 us; speedup vs baseline: 1.1289x; 1.1289x over previous
//
#include <hip/hip_runtime.h>
#include <cstdint>
#include <cstddef>

typedef unsigned short u16;
typedef __attribute__((ext_vector_type(8))) __bf16 bf16x8;
typedef __attribute__((ext_vector_type(4))) float f32x4;

#define S_LEN   2048
#define H_DIM   4096
#define NH_N    32
#define HD_N    128
#define QKV_LD  12288   // 3*H

// round-to-nearest-even fp32 -> bf16 (bit pattern)
__device__ __forceinline__ u16 f2b(float f) {
  union { float f; unsigned u; } v; v.f = f;
  unsigned r = v.u + 0x7fffu + ((v.u >> 16) & 1u);
  return (u16)(r >> 16);
}

// async global->LDS, 16B per lane; LDS dest = wave-uniform base + lane*16
__device__ __forceinline__ void gl2lds16(const void* g, void* l) {
  __builtin_amdgcn_global_load_lds((__attribute__((address_space(1))) void*)g,
                                   (__attribute__((address_space(3))) void*)l,
                                   16, 0, 0);
}

// ---------------------------------------------------------------- fp32->bf16
__global__ __launch_bounds__(256) void cvt_kernel(const float* __restrict__ src,
                                                  u16* __restrict__ dst, int n8) {
  int i = blockIdx.x * 256 + threadIdx.x;
  if (i >= n8) return;
  const float4* s4 = (const float4*)src;
  float4 a = s4[i * 2], b = s4[i * 2 + 1];
  union { u16 o[8]; uint4 v; } u;
  u.o[0] = f2b(a.x); u.o[1] = f2b(a.y); u.o[2] = f2b(a.z); u.o[3] = f2b(a.w);
  u.o[4] = f2b(b.x); u.o[5] = f2b(b.y); u.o[6] = f2b(b.z); u.o[7] = f2b(b.w);
  ((uint4*)dst)[i] = u.v;
}

// ------------------------------------------------------------------- GEMM
// C = A(MxK,bf16) * B(NxK,bf16)^T + bias ;  OUTF32: +residual -> f32 out
template <int OUTF32>
__global__ __launch_bounds__(256, 2)
void gemm_kernel(const u16* __restrict__ A, const u16* __restrict__ B,
                 const float* __restrict__ bias, const float* __restrict__ resid,
                 u16* __restrict__ outB, float* __restrict__ outF,
                 int M, int N, int K) {
  __shared__ __align__(16) u16 As[128 * 64];
  __shared__ __align__(16) u16 Bs[128 * 64];
  const int tid  = threadIdx.x;
  const int lane = tid & 63;
  const int wave = tid >> 6;
  const int l15  = lane & 15;
  const int quad = lane >> 4;
  const int m0 = blockIdx.y * 128;
  const int n0 = blockIdx.x * 128;
  const int wm = (wave & 1) * 64;
  const int wn = (wave >> 1) * 64;

  f32x4 acc[4][4] = {};

  int sRow[4], sCol[4];
#pragma unroll
  for (int it = 0; it < 4; ++it) {
    int slot = wave * 256 + it * 64 + lane;
    int row  = slot >> 3;
    int kc   = (slot & 7) ^ (row & 7);
    sRow[it] = row;
    sCol[it] = kc * 8;
  }
  const u16* Ag = A + (size_t)m0 * K;
  const u16* Bg = B + (size_t)n0 * K;

  for (int kb = 0; kb < K; kb += 64) {
#pragma unroll
    for (int it = 0; it < 4; ++it) {
      int base = (wave * 256 + it * 64) * 8;
      gl2lds16(Ag + (size_t)sRow[it] * K + kb + sCol[it], &As[base]);
      gl2lds16(Bg + (size_t)sRow[it] * K + kb + sCol[it], &Bs[base]);
    }
    __syncthreads();
#pragma unroll
    for (int s = 0; s < 2; ++s) {
      const int kc = s * 4 + quad;
      bf16x8 af[4], bfr[4];
#pragma unroll
      for (int i = 0; i < 4; ++i) {
        int ra = wm + i * 16 + l15;
        af[i]  = *(const bf16x8*)&As[(ra * 8 + (kc ^ (ra & 7))) * 8];
        int rb = wn + i * 16 + l15;
        bfr[i] = *(const bf16x8*)&Bs[(rb * 8 + (kc ^ (rb & 7))) * 8];
      }
#pragma unroll
      for (int i = 0; i < 4; ++i)
#pragma unroll
        for (int j = 0; j < 4; ++j)
          acc[i][j] = __builtin_amdgcn_mfma_f32_16x16x32_bf16(af[i], bfr[j], acc[i][j], 0, 0, 0);
    }
    __syncthreads();
  }

  float bcol[4];
#pragma unroll
  for (int j = 0; j < 4; ++j) bcol[j] = bias[n0 + wn + j * 16 + l15];
#pragma unroll
  for (int i = 0; i < 4; ++i) {
    int rowb = m0 + wm + i * 16 + quad * 4;
#pragma unroll
    for (int r = 0; r < 4; ++r) {
      size_t rowoff = (size_t)(rowb + r) * N;
#pragma unroll
      for (int j = 0; j < 4; ++j) {
        int col = n0 + wn + j * 16 + l15;
        float v = acc[i][j][r] + bcol[j];
        if (OUTF32) outF[rowoff + col] = v + resid[rowoff + col];
        else        outB[rowoff + col] = f2b(v);
      }
    }
  }
}

// ------------------------------------------------------------- attention
// Single q-tile (64 rows) per block, register-light (no spills).
// (head,qt) swizzled so co-resident blocks on a CU have qt {A,31-A,A+8,23-A}
// -> constant per-CU work. K/V for tile kt+1 prefetched into REGISTERS
// during tile-kt compute, ds_written to the alternate LDS buffer after
// compute -> global latency overlaps compute; barrier drains only LDS.
__global__ __launch_bounds__(256, 2)
void attn_kernel(const u16* __restrict__ QKV, const float* __restrict__ alibi,
                 u16* __restrict__ CTX) {
  __shared__ __align__(16) u16 Ks[2][64 * 128];   // swizzled [key][hd]
  __shared__ __align__(16) u16 Vt[2][128 * 64];   // swizzled [hd][key]
  __shared__ __align__(16) u16 Ps[4 * 1024];      // per-wave [q][key]
  const int tid  = threadIdx.x;
  const int lane = tid & 63;
  const int wave = tid >> 6;
  const int l15  = lane & 15;
  const int quad = lane >> 4;

  // balanced (head, qt) mapping: co-resident blocks (b +=256) get
  // qt = {A, 31-A, A+8, 31-(A+8)} -> 66 iterations per CU, constant.
  const int bidx = blockIdx.x;
  const int t8   = bidx & 31;
  const int h    = bidx >> 5;
  const int head = h;
  int A = (t8 + (h & 7)) & 31;
  if (h & 16) A = (A + 8) & 31;
  const int qt = (h & 8) ? (31 - A) : A;

  const int q0   = qt * 64;
  const int nk   = qt + 1;
  const int qcol = head * 384;
  const int kcol = qcol + 128;
  const int vcol = qcol + 256;
  const float c1 = 0.08838834764831845f * 1.4426950408889634f;  // invsqrt(128)*log2e
  const float slope2 = alibi[head * S_LEN + 1] * 1.4426950408889634f;

  // K prefetch: thread covers key=tid>>2, hd [khd, khd+32) -- 64B contiguous
  const int krow = tid >> 2;
  const int khd  = (tid & 3) * 32;
  // V prefetch: thread covers 4 keys x 8 hd
  const int vkey = (tid & 15) * 4;
  const int vhd  = (tid >> 4) * 8;

  auto load_k = [&](int kt, uint4* kr) {
    const uint4* p = (const uint4*)(QKV + (size_t)(kt * 64 + krow) * QKV_LD + kcol + khd);
#pragma unroll
    for (int c = 0; c < 4; ++c) kr[c] = p[c];
  };
  auto write_k = [&](int bb, const uint4* kr) {
#pragma unroll
    for (int c = 0; c < 4; ++c) {
      int kc = (tid & 3) * 4 + c;
      *(uint4*)&Ks[bb][(krow * 16 + (kc ^ (krow & 15))) * 8] = kr[c];
    }
  };
  auto load_v = [&](int kt, uint4* vr) {
    const u16* vp = QKV + (size_t)(kt * 64 + vkey) * QKV_LD + vcol + vhd;
#pragma unroll
    for (int j = 0; j < 4; ++j) vr[j] = *(const uint4*)(vp + (size_t)j * QKV_LD);
  };
  auto write_v = [&](int bb, const uint4* vr) {
    const u16* e0 = (const u16*)&vr[0];
    const u16* e1 = (const u16*)&vr[1];
    const u16* e2 = (const u16*)&vr[2];
    const u16* e3 = (const u16*)&vr[3];
#pragma unroll
    for (int u = 0; u < 8; ++u) {
      int hd = vhd + u;                       // hd & 7 == u
      uint2 w;
      w.x = (unsigned)e0[u] | ((unsigned)e1[u] << 16);
      w.y = (unsigned)e2[u] | ((unsigned)e3[u] << 16);
      *(uint2*)&Vt[bb][hd * 64 + ((vkey >> 3) ^ (hd & 7)) * 8 + (vkey & 7)] = w;
    }
  };

  // Q fragments stay in registers for the whole K loop
  bf16x8 qf[4];
  {
    const u16* qp = QKV + (size_t)(q0 + wave * 16 + l15) * QKV_LD + qcol;
#pragma unroll
    for (int s = 0; s < 4; ++s) qf[s] = *(const bf16x8*)(qp + s * 32 + quad * 8);
  }

  float m_i[4], l_i[4];
#pragma unroll
  for (int r = 0; r < 4; ++r) { m_i[r] = -3.0e38f; l_i[r] = 0.0f; }
  f32x4 acc[8] = {};

  // prologue: stage tile 0 into buffer 0
  {
    uint4 kr[4], vr[4];
    load_k(0, kr); load_v(0, vr);
    write_k(0, kr); write_v(0, vr);
    __syncthreads();
  }

  for (int kt = 0; kt < nk; ++kt) {
    const int cur = kt & 1;
    const bool more = (kt + 1 < nk);
    uint4 kr[4], vr[4];
    if (more) { load_k(kt + 1, kr); load_v(kt + 1, vr); }

    const int k0 = kt * 64;
    const u16* Ksc = Ks[cur];
    const u16* Vtc = Vt[cur];

    // Q*K^T : 16 rows x 64 keys per wave
    f32x4 sc[4] = {};
#pragma unroll
    for (int s = 0; s < 4; ++s) {
      const int kc = s * 4 + quad;
      bf16x8 kf[4];
#pragma unroll
      for (int j = 0; j < 4; ++j) {
        int row = j * 16 + l15;
        kf[j] = *(const bf16x8*)&Ksc[(row * 16 + (kc ^ (row & 15))) * 8];
      }
#pragma unroll
      for (int j = 0; j < 4; ++j)
        sc[j] = __builtin_amdgcn_mfma_f32_16x16x32_bf16(qf[s], kf[j], sc[j], 0, 0, 0);
    }

    // scores (log2 domain) + alibi + causal mask on diagonal tile
    const bool diag = (kt == qt);
    float mt[4] = { -3.0e38f, -3.0e38f, -3.0e38f, -3.0e38f };
#pragma unroll
    for (int j = 0; j < 4; ++j) {
      int key  = k0 + j * 16 + l15;
      float al = slope2 * (float)key;
#pragma unroll
      for (int r = 0; r < 4; ++r) {
        float x = sc[j][r] * c1 + al;
        if (diag) {
          int qrow = q0 + wave * 16 + quad * 4 + r;
          if (key > qrow) x = -3.0e38f;
        }
        sc[j][r] = x;
        mt[r] = fmaxf(mt[r], x);
      }
    }
#pragma unroll
    for (int r = 0; r < 4; ++r) {
      float v = mt[r];
      v = fmaxf(v, __shfl_xor(v, 1));
      v = fmaxf(v, __shfl_xor(v, 2));
      v = fmaxf(v, __shfl_xor(v, 4));
      v = fmaxf(v, __shfl_xor(v, 8));
      mt[r] = fmaxf(m_i[r], v);
    }
    float psum[4];
#pragma unroll
    for (int r = 0; r < 4; ++r) {
      float alpha = exp2f(m_i[r] - mt[r]);
      m_i[r] = mt[r];
      l_i[r] *= alpha;
      psum[r] = 0.0f;
#pragma unroll
      for (int u = 0; u < 8; ++u) acc[u][r] *= alpha;
    }
#pragma unroll
    for (int j = 0; j < 4; ++j) {
      int col = j * 16 + l15;
      int kc2 = col >> 3;
#pragma unroll
      for (int r = 0; r < 4; ++r) {
        float p = exp2f(sc[j][r] - m_i[r]);
        psum[r] += p;
        int qrow = quad * 4 + r;
        Ps[wave * 1024 + (qrow * 8 + (kc2 ^ (qrow & 7))) * 8 + (col & 7)] = f2b(p);
      }
    }
#pragma unroll
    for (int r = 0; r < 4; ++r) {
      float v = psum[r];
      v += __shfl_xor(v, 1);
      v += __shfl_xor(v, 2);
      v += __shfl_xor(v, 4);
      v += __shfl_xor(v, 8);
      l_i[r] += v;
    }

    // P*V : same-wave LDS write->read (in-order), no barrier needed
#pragma unroll
    for (int s = 0; s < 2; ++s) {
      const int kc = s * 4 + quad;
      bf16x8 pf = *(const bf16x8*)&Ps[wave * 1024 + (l15 * 8 + (kc ^ (l15 & 7))) * 8];
#pragma unroll
      for (int u = 0; u < 8; ++u) {
        int row = u * 16 + l15;
        bf16x8 vf = *(const bf16x8*)&Vtc[(row * 8 + (kc ^ (row & 7))) * 8];
        acc[u] = __builtin_amdgcn_mfma_f32_16x16x32_bf16(pf, vf, acc[u], 0, 0, 0);
      }
    }

    // stage next tile into the other buffer (vmcnt wait lands here,
    // after ~1k cycles of compute -> latency hidden)
    if (more) { write_k(cur ^ 1, kr); write_v(cur ^ 1, vr); }
    __syncthreads();
  }

  // normalize and write context (bf16) in [s][n*128+d] layout for GEMM2
#pragma unroll
  for (int r = 0; r < 4; ++r) {
    float inv = 1.0f / l_i[r];
    size_t rowoff = (size_t)(q0 + wave * 16 + quad * 4 + r) * H_DIM;
#pragma unroll
    for (int u = 0; u < 8; ++u)
      CTX[rowoff + head * HD_N + u * 16 + l15] = f2b(acc[u][r] * inv);
  }
}

// ---------------------------------------------------------------- launcher
extern "C" void kernel_launch(void* const* d_in, const int* in_sizes, int n_in,
                              void* d_out, int out_size, void* d_ws, size_t ws_size,
                              hipStream_t stream) {
  const float* hidden   = (const float*)d_in[0];
  const float* residual = (const float*)d_in[1];
  const float* alibi    = (const float*)d_in[2];
  // d_in[3] attention_mask: known causal, unused
  const float* qkv_w    = (const float*)d_in[4];
  const float* qkv_b    = (const float*)d_in[5];
  const float* dense_w  = (const float*)d_in[6];
  const float* dense_b  = (const float*)d_in[7];
  float* out = (float*)d_out;

  // workspace layout (bf16): X | Wqkv | Wdense | QKV | CTX
  u16* Xb  = (u16*)d_ws;
  u16* Wq  = Xb + (size_t)S_LEN * H_DIM;
  u16* Wd  = Wq + (size_t)3 * H_DIM * H_DIM;
  u16* QKV = Wd + (size_t)H_DIM * H_DIM;
  u16* CTX = QKV + (size_t)S_LEN * 3 * H_DIM;

  {
    int n8 = S_LEN * H_DIM / 8;
    cvt_kernel<<<dim3((n8 + 255) / 256), 256, 0, stream>>>(hidden, Xb, n8);
  }
  {
    int n8 = 3 * H_DIM * H_DIM / 8;
    cvt_kernel<<<dim3((n8 + 255) / 256), 256, 0, stream>>>(qkv_w, Wq, n8);
  }
  {
    int n8 = H_DIM * H_DIM / 8;
    cvt_kernel<<<dim3((n8 + 255) / 256), 256, 0, stream>>>(dense_w, Wd, n8);
  }

  // QKV = X * Wqkv^T + b  -> bf16
  gemm_kernel<0><<<dim3(3 * H_DIM / 128, S_LEN / 128), 256, 0, stream>>>(
      Xb, Wq, qkv_b, nullptr, QKV, nullptr, S_LEN, 3 * H_DIM, H_DIM);

  // flash attention -> CTX bf16 (1024 blocks, swizzled head/qt mapping)
  attn_kernel<<<dim3(1024), 256, 0, stream>>>(QKV, alibi, CTX);

  // out = CTX * Wd^T + b + residual  -> f32
  gemm_kernel<1><<<dim3(H_DIM / 128, S_LEN / 128), 256, 0, stream>>>(
      CTX, Wd, dense_b, residual, nullptr, out, S_LEN, H_DIM, H_DIM);
}